// Round 12
// baseline (253.409 us; speedup 1.0000x reference)
//
#include <hip/hip_runtime.h>
#include <cstdint>
#include <cstddef>

#define NSLOPE 0.2f
#define CAP 96   // bucket capacity per node; P(Poisson(16) > 96) ~ 1e-47

typedef __attribute__((ext_vector_type(8))) short bf16x8;
typedef __attribute__((ext_vector_type(4))) float f32x4;
typedef __attribute__((ext_vector_type(2))) float f32x2;
typedef unsigned short ushort_t;

// ---------------------------------------------------------------- utilities
__device__ inline ushort_t f2bf(float f) {
    union { float f; unsigned u; } v; v.f = f;
    unsigned u = v.u;
    unsigned r = (u + 0x7fffu + ((u >> 16) & 1u)) >> 16;   // RNE
    return (ushort_t)r;
}
// optimal 2-op unpack: lo = u<<16, hi = u & 0xffff0000
__device__ inline f32x2 unpack2(unsigned u) {
    union { unsigned u; float f; } lo, hi;
    lo.u = u << 16;
    hi.u = u & 0xffff0000u;
    f32x2 r; r.x = lo.f; r.y = hi.f;
    return r;
}
__device__ inline float leaky(float v) { return (v > 0.f) ? v : NSLOPE * v; }
__device__ inline float sel4(float4 q, bool b1, bool b2) {
    return b2 ? (b1 ? q.w : q.z) : (b1 ? q.y : q.x);
}

// ---------------------------------------------------------------- prep
// R12: memset dispatch eliminated. cnt-zeroing is now a prep SECTION; svec
// atomics (which required pre-zeroed svec) replaced by race-free direct-write
// partials svec_part[16][512], reduced in GEMM1's prologue. Edge scatter moved
// OUT of prep into GEMM1's grid (appended rows) — prep completing guarantees
// cnt is zeroed before GEMM1's scatter atomics. 5 dispatches total.
// sections: [0,384) transpose W1 | [..+64) transpose W2 | [..+32) svec_part |
// [..+nbCast) cast x->bf16 | [..+nbZero) zero cnt
__global__ __launch_bounds__(256) void prep_kernel(
    const float* __restrict__ x, ushort_t* __restrict__ x_bf16, size_t nx,
    const float* __restrict__ W1, ushort_t* __restrict__ W1T,
    const float* __restrict__ W2, ushort_t* __restrict__ W2T,
    const float* __restrict__ sent, float* __restrict__ svec_part,
    int* __restrict__ cnt, int N, int nbCast)
{
    __shared__ float tile[32][33];
    int bid = blockIdx.x;
    int tid = threadIdx.x;
    if (bid < 384) {   // W1[768][512] -> W1T[512][768]
        int k0 = (bid % 24) * 32, n0 = (bid / 24) * 32;
        int tx = tid & 31, ty = tid >> 5;
#pragma unroll
        for (int i = 0; i < 4; ++i)
            tile[ty + i * 8][tx] = W1[(size_t)(k0 + ty + i * 8) * 512 + n0 + tx];
        __syncthreads();
#pragma unroll
        for (int i = 0; i < 4; ++i)
            W1T[(size_t)(n0 + ty + i * 8) * 768 + k0 + tx] = f2bf(tile[tx][ty + i * 8]);
        return;
    }
    bid -= 384;
    if (bid < 64) {    // W2[512][128] -> W2T[128][512]
        int k0 = (bid % 16) * 32, n0 = (bid / 16) * 32;
        int tx = tid & 31, ty = tid >> 5;
#pragma unroll
        for (int i = 0; i < 4; ++i)
            tile[ty + i * 8][tx] = W2[(size_t)(k0 + ty + i * 8) * 128 + n0 + tx];
        __syncthreads();
#pragma unroll
        for (int i = 0; i < 4; ++i)
            W2T[(size_t)(n0 + ty + i * 8) * 512 + k0 + tx] = f2bf(tile[tx][ty + i * 8]);
        return;
    }
    bid -= 64;
    if (bid < 32) {    // svec partials: 2 col-halves x 16 k-chunks of 48, direct store
        int cb = bid & 1, kb = bid >> 1;
        int c = cb * 256 + tid;
        int k0 = kb * 48;
        float acc = 0.f;
#pragma unroll 8
        for (int k = k0; k < k0 + 48; ++k)
            acc += sent[k] * W1[(size_t)(768 + k) * 512 + c];
        svec_part[kb * 512 + c] = acc;   // race-free: unique (kb,c) per thread
        return;
    }
    bid -= 32;
    if (bid < nbCast) {   // cast x -> bf16
        size_t i = ((size_t)bid * 256 + tid) * 8;
        if (i < nx) {
            float4 v0 = *(const float4*)(x + i);
            float4 v1 = *(const float4*)(x + i + 4);
            ushort_t r[8] = { f2bf(v0.x), f2bf(v0.y), f2bf(v0.z), f2bf(v0.w),
                              f2bf(v1.x), f2bf(v1.y), f2bf(v1.z), f2bf(v1.w) };
            *(uint4*)(x_bf16 + i) = *(uint4*)r;
        }
        return;
    }
    bid -= nbCast;
    {                  // zero bucket counters (replaces hipMemsetAsync)
        int i = bid * 256 + tid;
        if (i < N) cnt[i] = 0;
    }
}

// ---------------------------------------------------------------- MFMA GEMM
// 64-row x 128-col tiles (R4), 4-DEEP pipeline (R9), XCD-aware bijective
// swizzle (requires gridDim.y % 8 == 0; role decoded from SWIZZLED by, so
// bijectivity holds). R12: rows with by >= nyReal are edge-SCATTER blocks
// (1 atomic slot + 1 store per thread) that backfill the gemm tail — the
// scatter dispatch is gone. bias comes from nPart partials (svec_part for
// GEMM1, reduced once per thread in the prologue; nPart=0 -> zero bias).
// Fused attention-coefficient epilogue writes e_src/e_dst[row*eStride + bx].
__device__ inline void async_copy16(const void* g, void* l) {
    __builtin_amdgcn_global_load_lds(
        (const __attribute__((address_space(1))) unsigned int*)g,
        (__attribute__((address_space(3))) unsigned int*)l, 16, 0, 0);
}

__global__ __launch_bounds__(256) void mfma_gemm_kernel(
    const ushort_t* __restrict__ A,   // [M][K] bf16
    const ushort_t* __restrict__ BT,  // [Nc][K] bf16
    const float* __restrict__ bias_part, // [nPart][512] partials or null
    int nPart,
    ushort_t* __restrict__ Cb,        // [M][Nc] bf16
    const float* __restrict__ asrc,   // [Nc] flat attention vec (src)
    const float* __restrict__ adst,   // [Nc] flat attention vec (dst)
    float* __restrict__ e_src,        // [M*eStride]
    float* __restrict__ e_dst,
    int eStride,
    int M, int K, int Nc,
    int nyReal,                       // rows >= nyReal: scatter role
    const int* __restrict__ ei, int E,
    int* __restrict__ cnt, int* __restrict__ bucket)
{
    __shared__ __align__(16) ushort_t lA[4][64 * 32];
    __shared__ __align__(16) ushort_t lB[4][128 * 32];
    __shared__ float e_lds[64][2][2];   // [row_local][col_half][src/dst]
    const int tid = threadIdx.x;
    const int wave = tid >> 6;
    const int lane = tid & 63;

    // bijective XCD swizzle (m204 form). Requires gridDim.y % 8 == 0.
    const int hh = blockIdx.y * gridDim.x + blockIdx.x;
    const int xcd = hh & 7;
    const int slot = hh >> 3;
    const int by = xcd + 8 * (slot / gridDim.x);
    const int bx = slot % gridDim.x;

    if (by >= nyReal) {   // ---- scatter role (no LDS/barrier use) ----
        int sid = (by - nyReal) * gridDim.x + bx;
        int e = sid * 256 + tid;
        if (e < E) {
            int d = ei[E + e];
            int s = atomicAdd(&cnt[d], 1);
            if (s < CAP) bucket[d * CAP + s] = ei[e];
        }
        return;
    }

    const int col0 = bx * 128;
    const int row0 = by * 64;
    const int wm = (wave & 1) * 32;      // 2 waves over 64 rows
    const int wn = (wave >> 1) * 64;     // 2 waves over 128 cols
    const int q = lane >> 4;
    const int ml = lane & 15;

    // bias per output col (4 cols/thread), reduced from partials (L2-hot 32KB)
    float bb4[4];
#pragma unroll
    for (int tn = 0; tn < 4; ++tn) {
        int col = col0 + wn + tn * 16 + ml;
        float sum = 0.f;
        for (int kb = 0; kb < nPart; ++kb)
            sum += bias_part[kb * 512 + col];
        bb4[tn] = sum;
    }

    f32x4 acc[2][4] = {};

    // A: 1 load/thread (64 rows x 4 chunks); B: 2 loads/thread (128 rows)
    const int rA = tid >> 2;
    const int gA = (tid & 3) ^ ((rA >> 1) & 3);
    int rowS[2], gS[2];
#pragma unroll
    for (int i = 0; i < 2; ++i) {
        int p = wave * 128 + i * 64 + lane;
        int r = p >> 2, s = p & 3;
        rowS[i] = r;
        gS[i] = s ^ ((r >> 1) & 3);
    }

    // 3 global_load_lds per thread per stage (1 A + 2 B)
    auto stage = [&](int k0, int buf) {
        {
            int ga = min(row0 + rA, M - 1);
            async_copy16(A + (size_t)ga * K + k0 + gA * 8,
                         &lA[buf][(size_t)(wave * 64) * 8]);
        }
#pragma unroll
        for (int i = 0; i < 2; ++i) {
            int pbs = wave * 128 + i * 64;
            async_copy16(BT + (size_t)(col0 + rowS[i]) * K + k0 + gS[i] * 8,
                         &lB[buf][(size_t)pbs * 8]);
        }
    };

    const int nt = K >> 5;           // 24 (GEMM1) / 16 (GEMM2)
    stage(0, 0);
    if (nt > 2) {
        stage(32, 1);
        stage(64, 2);
        // in flight: t0(3) t1(3) t2(3); wait t0, keep t1/t2 flying
        asm volatile("s_waitcnt vmcnt(6)\n\ts_barrier" ::: "memory");
    } else if (nt > 1) {
        stage(32, 1);
        asm volatile("s_waitcnt vmcnt(3)\n\ts_barrier" ::: "memory");
    } else {
        asm volatile("s_waitcnt vmcnt(0)\n\ts_barrier" ::: "memory");
    }

    for (int t = 0; t < nt; ++t) {
        const int pb = t & 3;
        // stage writes buf (t+3)%4 == (t-1)%4: its readers (iter t-1) all
        // passed the barrier that ended iter t-1 (with lgkmcnt drained).
        if (t + 3 < nt) stage((t + 3) << 5, (t + 3) & 3);
        bf16x8 af[2], bfr[4];
#pragma unroll
        for (int tt = 0; tt < 2; ++tt) {
            int m = wm + tt * 16 + ml;
            af[tt] = *(const bf16x8*)&lA[pb][(size_t)(m * 4 + (q ^ ((m >> 1) & 3))) * 8];
        }
#pragma unroll
        for (int tt = 0; tt < 4; ++tt) {
            int n = wn + tt * 16 + ml;
            bfr[tt] = *(const bf16x8*)&lB[pb][(size_t)(n * 4 + (q ^ ((n >> 1) & 3))) * 8];
        }
#pragma unroll
        for (int tm = 0; tm < 2; ++tm)
#pragma unroll
            for (int tn = 0; tn < 4; ++tn)
                acc[tm][tn] = __builtin_amdgcn_mfma_f32_16x16x32_bf16(
                    af[tm], bfr[tn], acc[tm][tn], 0, 0, 0);
        // end-of-iter: tile t+1 landed; t+2 (and t+3 if staged) stay IN FLIGHT.
        if (t + 3 < nt)
            asm volatile("s_waitcnt vmcnt(6) lgkmcnt(0)\n\ts_barrier" ::: "memory");
        else if (t + 2 < nt)
            asm volatile("s_waitcnt vmcnt(3) lgkmcnt(0)\n\ts_barrier" ::: "memory");
        else if (t + 1 < nt)
            asm volatile("s_waitcnt vmcnt(0) lgkmcnt(0)\n\ts_barrier" ::: "memory");
        // last iteration: no barrier needed; epilogue __syncthreads covers e_lds.
    }

    float es_acc[2][4] = {};   // [tm][r]
    float ed_acc[2][4] = {};
#pragma unroll
    for (int tm = 0; tm < 2; ++tm) {
        int rbase = row0 + wm + tm * 16 + q * 4;
#pragma unroll
        for (int tn = 0; tn < 4; ++tn) {
            int col = col0 + wn + tn * 16 + ml;
            float bb = bb4[tn];
            float av = asrc[col];
            float dv = adst[col];
#pragma unroll
            for (int r = 0; r < 4; ++r) {
                int row = rbase + r;
                float val = acc[tm][tn][r] + bb;
                if (row < M)
                    Cb[(size_t)row * Nc + col] = f2bf(val);
                es_acc[tm][r] += val * av;
                ed_acc[tm][r] += val * dv;
            }
        }
    }
    // reduce over the 16-lane col groups (xor 1,2,4,8 keeps q fixed)
    const int colhalf = wave >> 1;
#pragma unroll
    for (int tm = 0; tm < 2; ++tm) {
#pragma unroll
        for (int r = 0; r < 4; ++r) {
            float es = es_acc[tm][r], ed2 = ed_acc[tm][r];
#pragma unroll
            for (int st = 1; st < 16; st <<= 1) {
                es += __shfl_xor(es, st);
                ed2 += __shfl_xor(ed2, st);
            }
            if (ml == 0) {
                int rl = wm + tm * 16 + q * 4 + r;
                e_lds[rl][colhalf][0] = es;
                e_lds[rl][colhalf][1] = ed2;
            }
        }
    }
    __syncthreads();
    if (tid < 64) {
        int row = row0 + tid;
        if (row < M) {
            float es = e_lds[tid][0][0] + e_lds[tid][1][0];
            float ed2 = e_lds[tid][0][1] + e_lds[tid][1][1];
            e_src[(size_t)row * eStride + bx] = es;
            e_dst[(size_t)row * eStride + bx] = ed2;
        }
    }
}

// ---------------------------------------------------------------- gather+softmax
// layer 1: persistent waves (R6), A/B load pipeline (R5), unnormalized softmax
// (R2), bucket-indexed (R10). Unchanged from R11.
__global__ __launch_bounds__(256) void gather1_kernel(
    const ushort_t* __restrict__ h1b, const float* __restrict__ e_src,
    const float* __restrict__ e_dst, const int* __restrict__ cnt,
    const int* __restrict__ bucket, const float* __restrict__ bias,
    ushort_t* __restrict__ outb, int N)
{
    const int lane = threadIdx.x & 63;
    const int wid0 = blockIdx.x * 4 + (threadIdx.x >> 6);
    const int nw = gridDim.x * 4;

    const int h = lane >> 4;
    const bool b1 = (h & 1), b2 = (h & 2);
    const ushort_t* hp = h1b + lane * 8;
    const int c = lane * 8;
    float bias0 = bias[c],     bias1 = bias[c + 1], bias2 = bias[c + 2],
          bias3 = bias[c + 3], bias4 = bias[c + 4], bias5 = bias[c + 5],
          bias6 = bias[c + 6], bias7 = bias[c + 7];

    for (int node = __builtin_amdgcn_readfirstlane(wid0); node < N;
         node = __builtin_amdgcn_readfirstlane(node + nw)) {
        int deg = cnt[node];
        if (deg > CAP) deg = CAP;
        int beg = node * CAP, end = beg + deg;
        float4 ed = *(const float4*)&e_dst[node * 4];
        float edh = sel4(ed, b1, b2);

        f32x2 acc[4] = {};
        float s = 0.f;                   // same value in every lane of a head

        int j = beg;
        const int nb = deg >> 2;

        int4 ia, ib;
        float4 qa0, qa1, qa2, qa3, qb0, qb1, qb2, qb3;
        uint4 ua0, ua1, ua2, ua3, ub0, ub1, ub2, ub3;

        auto load4 = [&](int jj, int4& ix,
                         float4& q0, float4& q1, float4& q2, float4& q3,
                         uint4& u0, uint4& u1, uint4& u2, uint4& u3) {
            ix.x = bucket[jj];     ix.y = bucket[jj + 1];
            ix.z = bucket[jj + 2]; ix.w = bucket[jj + 3];
            q0 = *(const float4*)&e_src[ix.x * 4];
            q1 = *(const float4*)&e_src[ix.y * 4];
            q2 = *(const float4*)&e_src[ix.z * 4];
            q3 = *(const float4*)&e_src[ix.w * 4];
            u0 = *(const uint4*)&hp[(size_t)ix.x * 512];
            u1 = *(const uint4*)&hp[(size_t)ix.y * 512];
            u2 = *(const uint4*)&hp[(size_t)ix.z * 512];
            u3 = *(const uint4*)&hp[(size_t)ix.w * 512];
        };
        auto cons4 = [&](const float4& q0, const float4& q1,
                         const float4& q2, const float4& q3,
                         const uint4& u0, const uint4& u1,
                         const uint4& u2, const uint4& u3) {
            float w0 = __expf(leaky(sel4(q0, b1, b2) + edh));
            float w1 = __expf(leaky(sel4(q1, b1, b2) + edh));
            float w2 = __expf(leaky(sel4(q2, b1, b2) + edh));
            float w3 = __expf(leaky(sel4(q3, b1, b2) + edh));
            s += (w0 + w1) + (w2 + w3);
            f32x2 wv;
            wv.x = w0; wv.y = w0;
            acc[0] += unpack2(u0.x) * wv; acc[1] += unpack2(u0.y) * wv;
            acc[2] += unpack2(u0.z) * wv; acc[3] += unpack2(u0.w) * wv;
            wv.x = w1; wv.y = w1;
            acc[0] += unpack2(u1.x) * wv; acc[1] += unpack2(u1.y) * wv;
            acc[2] += unpack2(u1.z) * wv; acc[3] += unpack2(u1.w) * wv;
            wv.x = w2; wv.y = w2;
            acc[0] += unpack2(u2.x) * wv; acc[1] += unpack2(u2.y) * wv;
            acc[2] += unpack2(u2.z) * wv; acc[3] += unpack2(u2.w) * wv;
            wv.x = w3; wv.y = w3;
            acc[0] += unpack2(u3.x) * wv; acc[1] += unpack2(u3.y) * wv;
            acc[2] += unpack2(u3.z) * wv; acc[3] += unpack2(u3.w) * wv;
        };

        if (nb > 0) {
            load4(j, ia, qa0, qa1, qa2, qa3, ua0, ua1, ua2, ua3); j += 4;
            int b = 1;
            for (; b + 1 < nb; b += 2) {
                load4(j, ib, qb0, qb1, qb2, qb3, ub0, ub1, ub2, ub3); j += 4;
                cons4(qa0, qa1, qa2, qa3, ua0, ua1, ua2, ua3);
                load4(j, ia, qa0, qa1, qa2, qa3, ua0, ua1, ua2, ua3); j += 4;
                cons4(qb0, qb1, qb2, qb3, ub0, ub1, ub2, ub3);
            }
            if (b < nb) {
                load4(j, ib, qb0, qb1, qb2, qb3, ub0, ub1, ub2, ub3); j += 4;
                cons4(qa0, qa1, qa2, qa3, ua0, ua1, ua2, ua3);
                cons4(qb0, qb1, qb2, qb3, ub0, ub1, ub2, ub3);
            } else {
                cons4(qa0, qa1, qa2, qa3, ua0, ua1, ua2, ua3);
            }
        }
        for (; j < end; ++j) {
            int s0 = bucket[j];
            float4 q0 = *(const float4*)&e_src[s0 * 4];
            float w0 = __expf(leaky(sel4(q0, b1, b2) + edh));
            s += w0;
            uint4 u0 = *(const uint4*)&hp[(size_t)s0 * 512];
            f32x2 wv; wv.x = w0; wv.y = w0;
            acc[0] += unpack2(u0.x) * wv; acc[1] += unpack2(u0.y) * wv;
            acc[2] += unpack2(u0.z) * wv; acc[3] += unpack2(u0.w) * wv;
        }
        float rs = 1.f / (s + 1e-16f);
        ushort_t o[8];
        float r0, r1;
        r0 = acc[0].x * rs + bias0; r1 = acc[0].y * rs + bias1;
        r0 = (r0 > 0.f) ? r0 : (__expf(r0) - 1.f);
        r1 = (r1 > 0.f) ? r1 : (__expf(r1) - 1.f);
        o[0] = f2bf(r0); o[1] = f2bf(r1);
        r0 = acc[1].x * rs + bias2; r1 = acc[1].y * rs + bias3;
        r0 = (r0 > 0.f) ? r0 : (__expf(r0) - 1.f);
        r1 = (r1 > 0.f) ? r1 : (__expf(r1) - 1.f);
        o[2] = f2bf(r0); o[3] = f2bf(r1);
        r0 = acc[2].x * rs + bias4; r1 = acc[2].y * rs + bias5;
        r0 = (r0 > 0.f) ? r0 : (__expf(r0) - 1.f);
        r1 = (r1 > 0.f) ? r1 : (__expf(r1) - 1.f);
        o[4] = f2bf(r0); o[5] = f2bf(r1);
        r0 = acc[3].x * rs + bias6; r1 = acc[3].y * rs + bias7;
        r0 = (r0 > 0.f) ? r0 : (__expf(r0) - 1.f);
        r1 = (r1 > 0.f) ? r1 : (__expf(r1) - 1.f);
        o[6] = f2bf(r0); o[7] = f2bf(r1);
        *(uint4*)&outb[(size_t)node * 512 + c] = *(uint4*)o;
    }
}

// layer 2: persistent waves, 1 head; bucket-indexed; fp32 out. Unchanged.
__global__ __launch_bounds__(256) void gather2_kernel(
    const ushort_t* __restrict__ h2b, const float* __restrict__ e_src,
    const float* __restrict__ e_dst, const int* __restrict__ cnt,
    const int* __restrict__ bucket, const float* __restrict__ bias,
    float* __restrict__ out, int N)
{
    const int lane = threadIdx.x & 63;
    const int wid0 = blockIdx.x * 4 + (threadIdx.x >> 6);
    const int nw = gridDim.x * 4;

    const ushort_t* hp = h2b + lane * 2;
    float biasA = bias[lane * 2], biasB = bias[lane * 2 + 1];

    for (int node = __builtin_amdgcn_readfirstlane(wid0); node < N;
         node = __builtin_amdgcn_readfirstlane(node + nw)) {
        int deg = cnt[node];
        if (deg > CAP) deg = CAP;
        int beg = node * CAP, end = beg + deg;
        float ed = e_dst[node];

        f32x2 acc = { 0.f, 0.f };
        float s = 0.f;

        int j = beg;
        const int nb = deg >> 2;

        int4 ia, ib;
        float fa0, fa1, fa2, fa3, fb0, fb1, fb2, fb3;
        unsigned ua0, ua1, ua2, ua3, ub0, ub1, ub2, ub3;

        auto load4 = [&](int jj, int4& ix,
                         float& f0, float& f1, float& f2, float& f3,
                         unsigned& u0, unsigned& u1, unsigned& u2, unsigned& u3) {
            ix.x = bucket[jj];     ix.y = bucket[jj + 1];
            ix.z = bucket[jj + 2]; ix.w = bucket[jj + 3];
            f0 = e_src[ix.x]; f1 = e_src[ix.y];
            f2 = e_src[ix.z]; f3 = e_src[ix.w];
            u0 = *(const unsigned*)&hp[(size_t)ix.x * 128];
            u1 = *(const unsigned*)&hp[(size_t)ix.y * 128];
            u2 = *(const unsigned*)&hp[(size_t)ix.z * 128];
            u3 = *(const unsigned*)&hp[(size_t)ix.w * 128];
        };
        auto cons4 = [&](float f0, float f1, float f2, float f3,
                         unsigned u0, unsigned u1, unsigned u2, unsigned u3) {
            float w0 = __expf(leaky(f0 + ed));
            float w1 = __expf(leaky(f1 + ed));
            float w2 = __expf(leaky(f2 + ed));
            float w3 = __expf(leaky(f3 + ed));
            s += (w0 + w1) + (w2 + w3);
            f32x2 w0v = { w0, w0 }, w1v = { w1, w1 }, w2v = { w2, w2 }, w3v = { w3, w3 };
            acc += unpack2(u0) * w0v;
            acc += unpack2(u1) * w1v;
            acc += unpack2(u2) * w2v;
            acc += unpack2(u3) * w3v;
        };

        if (nb > 0) {
            load4(j, ia, fa0, fa1, fa2, fa3, ua0, ua1, ua2, ua3); j += 4;
            int b = 1;
            for (; b + 1 < nb; b += 2) {
                load4(j, ib, fb0, fb1, fb2, fb3, ub0, ub1, ub2, ub3); j += 4;
                cons4(fa0, fa1, fa2, fa3, ua0, ua1, ua2, ua3);
                load4(j, ia, fa0, fa1, fa2, fa3, ua0, ua1, ua2, ua3); j += 4;
                cons4(fb0, fb1, fb2, fb3, ub0, ub1, ub2, ub3);
            }
            if (b < nb) {
                load4(j, ib, fb0, fb1, fb2, fb3, ub0, ub1, ub2, ub3); j += 4;
                cons4(fa0, fa1, fa2, fa3, ua0, ua1, ua2, ua3);
                cons4(fb0, fb1, fb2, fb3, ub0, ub1, ub2, ub3);
            } else {
                cons4(fa0, fa1, fa2, fa3, ua0, ua1, ua2, ua3);
            }
        }
        for (; j < end; ++j) {
            int s0 = bucket[j];
            float w0 = __expf(leaky(e_src[s0] + ed));
            s += w0;
            unsigned u0 = *(const unsigned*)&hp[(size_t)s0 * 128];
            f32x2 w0v = { w0, w0 };
            acc += unpack2(u0) * w0v;
        }
        float rs = 1.f / (s + 1e-16f);
        float2 o = make_float2(acc.x * rs + biasA, acc.y * rs + biasB);
        *(float2*)&out[(size_t)node * 128 + lane * 2] = o;
    }
}

// ---------------------------------------------------------------- launch
extern "C" void kernel_launch(void* const* d_in, const int* in_sizes, int n_in,
                              void* d_out, int out_size, void* d_ws, size_t ws_size,
                              hipStream_t stream) {
    const float* x      = (const float*)d_in[0];
    const int*   ei     = (const int*)  d_in[1];
    const float* sent   = (const float*)d_in[2];
    const float* W1     = (const float*)d_in[3];
    const float* a1_src = (const float*)d_in[4];
    const float* a1_dst = (const float*)d_in[5];
    const float* b1     = (const float*)d_in[6];
    const float* W2     = (const float*)d_in[7];
    const float* a2_src = (const float*)d_in[8];
    const float* a2_dst = (const float*)d_in[9];
    const float* b2     = (const float*)d_in[10];
    float* out = (float*)d_out;

    const int N = in_sizes[0] / 768;   // 20000
    const int E = in_sizes[1] / 2;     // 320000

    char* p = (char*)d_ws;
    auto carve = [&](size_t bytes) {
        char* q = p;
        p += (bytes + 255) & ~(size_t)255;
        return q;
    };
    ushort_t* h1b = (ushort_t*)carve((size_t)N * 512 * 2);
    char* shared_region = carve((size_t)N * 768 * 2);   // x_bf16 dead after GEMM1
    ushort_t* x_bf16 = (ushort_t*)shared_region;
    ushort_t* h_elu_b = (ushort_t*)shared_region;
    ushort_t* h2b = (ushort_t*)carve((size_t)N * 128 * 2);
    ushort_t* W1T = (ushort_t*)carve((size_t)512 * 768 * 2);
    ushort_t* W2T = (ushort_t*)carve((size_t)128 * 512 * 2);
    float* svec_part = (float*)carve(16 * 512 * 4);
    float* e_src1 = (float*)carve((size_t)N * 4 * 4);
    float* e_dst1 = (float*)carve((size_t)N * 4 * 4);
    float* e_src2 = (float*)carve((size_t)N * 4);
    float* e_dst2 = (float*)carve((size_t)N * 4);
    int*   cnt    = (int*)carve((size_t)N * 4);
    int*   bucket = (int*)carve((size_t)N * CAP * 4);

    size_t nx = (size_t)N * 768;
    int nbCast = (int)((nx / 8 + 255) / 256);       // 7500
    int nbZero = (N + 255) / 256;                   // 79
    int nbPrep = 384 + 64 + 32 + nbCast + nbZero;   // 8059

    // 1) prep: transposes, svec partials, cast, zero cnt (memset folded in)
    prep_kernel<<<nbPrep, 256, 0, stream>>>(
        x, x_bf16, nx, W1, W1T, W2, W2T, sent, svec_part, cnt, N, nbCast);

    // GEMM1 grid: 320 real rows (64-row tiles, padded to %8) + scatter rows.
    int nyReal = (((N + 63) / 64) + 7) & ~7;        // 320
    int nbScat = (E + 255) / 256;                   // 1250
    int gy1 = nyReal + (nbScat + 3) / 4;            // 633
    gy1 = (gy1 + 7) & ~7;                           // 640 (gy%8==0 for swizzle)

    // 2) GEMM1 (+ edge scatter backfilling the tail): h1b, e1
    mfma_gemm_kernel<<<dim3(4, gy1), 256, 0, stream>>>(
        x_bf16, W1T, svec_part, 16, h1b, a1_src, a1_dst, e_src1, e_dst1,
        4, N, 768, 512, nyReal, ei, E, cnt, bucket);

    // 3) layer-1 attention: persistent waves, 2048 blocks = 8/CU
    gather1_kernel<<<2048, 256, 0, stream>>>(
        h1b, e_src1, e_dst1, cnt, bucket, b1, h_elu_b, N);

    // 4) GEMM2: h2b, e2 (no scatter rows, no bias partials)
    mfma_gemm_kernel<<<dim3(1, nyReal), 256, 0, stream>>>(
        h_elu_b, W2T, nullptr, 0, h2b, a2_src, a2_dst, e_src2, e_dst2,
        1, N, 512, 128, nyReal, nullptr, 0, nullptr, nullptr);

    // 5) layer-2 attention: persistent waves
    gather2_kernel<<<2048, 256, 0, stream>>>(
        h2b, e_src2, e_dst2, cnt, bucket, b2, out, N);
}

// Round 13
// 250.495 us; speedup vs baseline: 1.0116x; 1.0116x over previous
//
#include <hip/hip_runtime.h>
#include <cstdint>
#include <cstddef>

#define NSLOPE 0.2f
#define CAP 96   // bucket capacity per node; P(Poisson(16) > 96) ~ 1e-47

typedef __attribute__((ext_vector_type(8))) short bf16x8;
typedef __attribute__((ext_vector_type(4))) float f32x4;
typedef __attribute__((ext_vector_type(2))) float f32x2;
typedef unsigned short ushort_t;

// ---------------------------------------------------------------- utilities
__device__ inline ushort_t f2bf(float f) {
    union { float f; unsigned u; } v; v.f = f;
    unsigned u = v.u;
    unsigned r = (u + 0x7fffu + ((u >> 16) & 1u)) >> 16;   // RNE
    return (ushort_t)r;
}
// optimal 2-op unpack: lo = u<<16, hi = u & 0xffff0000
__device__ inline f32x2 unpack2(unsigned u) {
    union { unsigned u; float f; } lo, hi;
    lo.u = u << 16;
    hi.u = u & 0xffff0000u;
    f32x2 r; r.x = lo.f; r.y = hi.f;
    return r;
}
__device__ inline float leaky(float v) { return (v > 0.f) ? v : NSLOPE * v; }
__device__ inline float sel4(float4 q, bool b1, bool b2) {
    return b2 ? (b1 ? q.w : q.z) : (b1 ? q.y : q.x);
}

// ---------------------------------------------------------------- prep+scatter
// R13 = exact R11 revert (measured best, 251.2us). R12's scatter-into-GEMM1
// regressed: scatter blocks held the GEMM's 50KB static LDS (3 blocks/CU) and
// its 20MB partial-line bucket writeback contended with the GEMM stream
// (GEMM1 46->70us). Scatter belongs HERE: LDS-free kernel, 8 blocks/CU,
// overlapped with the cast's BW phase. sections:
// [0,384) transpose W1 | [..+64) transpose W2 | [..+32) svec partials
// (atomicAdd into memset-zeroed svec) | [..+nbCast) cast x->bf16 |
// rest: bucket scatter (atomicAdd slot, OOB-guarded)
__global__ __launch_bounds__(256) void prep_scatter_kernel(
    const float* __restrict__ x, ushort_t* __restrict__ x_bf16, size_t nx,
    const float* __restrict__ W1, ushort_t* __restrict__ W1T,
    const float* __restrict__ W2, ushort_t* __restrict__ W2T,
    const float* __restrict__ sent, float* __restrict__ svec,
    const int* __restrict__ ei, int E,
    int* __restrict__ cnt, int* __restrict__ bucket, int nbCast)
{
    __shared__ float tile[32][33];
    int bid = blockIdx.x;
    int tid = threadIdx.x;
    if (bid < 384) {   // W1[768][512] -> W1T[512][768]
        int k0 = (bid % 24) * 32, n0 = (bid / 24) * 32;
        int tx = tid & 31, ty = tid >> 5;
#pragma unroll
        for (int i = 0; i < 4; ++i)
            tile[ty + i * 8][tx] = W1[(size_t)(k0 + ty + i * 8) * 512 + n0 + tx];
        __syncthreads();
#pragma unroll
        for (int i = 0; i < 4; ++i)
            W1T[(size_t)(n0 + ty + i * 8) * 768 + k0 + tx] = f2bf(tile[tx][ty + i * 8]);
        return;
    }
    bid -= 384;
    if (bid < 64) {    // W2[512][128] -> W2T[128][512]
        int k0 = (bid % 16) * 32, n0 = (bid / 16) * 32;
        int tx = tid & 31, ty = tid >> 5;
#pragma unroll
        for (int i = 0; i < 4; ++i)
            tile[ty + i * 8][tx] = W2[(size_t)(k0 + ty + i * 8) * 128 + n0 + tx];
        __syncthreads();
#pragma unroll
        for (int i = 0; i < 4; ++i)
            W2T[(size_t)(n0 + ty + i * 8) * 512 + k0 + tx] = f2bf(tile[tx][ty + i * 8]);
        return;
    }
    bid -= 64;
    if (bid < 32) {    // svec partials: 2 col-halves x 16 k-chunks of 48
        int cb = bid & 1, kb = bid >> 1;
        int c = cb * 256 + tid;
        int k0 = kb * 48;
        float acc = 0.f;
#pragma unroll 8
        for (int k = k0; k < k0 + 48; ++k)
            acc += sent[k] * W1[(size_t)(768 + k) * 512 + c];
        atomicAdd(&svec[c], acc);   // svec pre-zeroed by the memset
        return;
    }
    bid -= 32;
    if (bid < nbCast) {   // cast x -> bf16
        size_t i = ((size_t)bid * 256 + tid) * 8;
        if (i < nx) {
            float4 v0 = *(const float4*)(x + i);
            float4 v1 = *(const float4*)(x + i + 4);
            ushort_t r[8] = { f2bf(v0.x), f2bf(v0.y), f2bf(v0.z), f2bf(v0.w),
                              f2bf(v1.x), f2bf(v1.y), f2bf(v1.z), f2bf(v1.w) };
            *(uint4*)(x_bf16 + i) = *(uint4*)r;
        }
        return;
    }
    bid -= nbCast;
    {                  // bucket scatter (cnt pre-zeroed via hipMemsetAsync)
        int e = bid * 256 + tid;
        if (e < E) {
            int d = ei[E + e];
            int slot = atomicAdd(&cnt[d], 1);
            if (slot < CAP) bucket[d * CAP + slot] = ei[e];
        }
    }
}

// ---------------------------------------------------------------- MFMA GEMM
// 64-row x 128-col tiles (R4), 4-DEEP pipeline (R9: GEMM1 52 -> <48us; 3 tiles
// in flight ~= full ~900cy HBM latency covered, counted vmcnt(6)). Same sync
// discipline: stage target (t+3)%4 == (t-1)%4, readers drained via lgkmcnt(0)
// at the barrier ending iter t-1. XCD-aware bijective swizzle (FETCH
// 61.6->20.0MB measured). Fused attention-coefficient epilogue.
__device__ inline void async_copy16(const void* g, void* l) {
    __builtin_amdgcn_global_load_lds(
        (const __attribute__((address_space(1))) unsigned int*)g,
        (__attribute__((address_space(3))) unsigned int*)l, 16, 0, 0);
}

__global__ __launch_bounds__(256) void mfma_gemm_kernel(
    const ushort_t* __restrict__ A,   // [M][K] bf16
    const ushort_t* __restrict__ BT,  // [Nc][K] bf16
    const float* __restrict__ bias,   // [Nc] or null
    ushort_t* __restrict__ Cb,        // [M][Nc] bf16
    const float* __restrict__ asrc,   // [Nc] flat attention vec (src)
    const float* __restrict__ adst,   // [Nc] flat attention vec (dst)
    float* __restrict__ e_src,        // [M*eStride]
    float* __restrict__ e_dst,
    int eStride,
    int M, int K, int Nc)
{
    __shared__ __align__(16) ushort_t lA[4][64 * 32];
    __shared__ __align__(16) ushort_t lB[4][128 * 32];
    __shared__ float e_lds[64][2][2];   // [row_local][col_half][src/dst]
    const int tid = threadIdx.x;
    const int wave = tid >> 6;
    const int lane = tid & 63;

    // bijective XCD swizzle (m204 form). Requires (gridDim.x*gridDim.y)%8==0.
    const int hh = blockIdx.y * gridDim.x + blockIdx.x;
    const int xcd = hh & 7;
    const int slot = hh >> 3;
    const int by = xcd + 8 * (slot / gridDim.x);
    const int bx = slot % gridDim.x;

    const int col0 = bx * 128;
    const int row0 = by * 64;
    const int wm = (wave & 1) * 32;      // 2 waves over 64 rows
    const int wn = (wave >> 1) * 64;     // 2 waves over 128 cols
    const int q = lane >> 4;
    const int ml = lane & 15;

    f32x4 acc[2][4] = {};

    // A: 1 load/thread (64 rows x 4 chunks); B: 2 loads/thread (128 rows)
    const int rA = tid >> 2;
    const int gA = (tid & 3) ^ ((rA >> 1) & 3);
    int rowS[2], gS[2];
#pragma unroll
    for (int i = 0; i < 2; ++i) {
        int p = wave * 128 + i * 64 + lane;
        int r = p >> 2, s = p & 3;
        rowS[i] = r;
        gS[i] = s ^ ((r >> 1) & 3);
    }

    // 3 global_load_lds per thread per stage (1 A + 2 B)
    auto stage = [&](int k0, int buf) {
        {
            int ga = min(row0 + rA, M - 1);
            async_copy16(A + (size_t)ga * K + k0 + gA * 8,
                         &lA[buf][(size_t)(wave * 64) * 8]);
        }
#pragma unroll
        for (int i = 0; i < 2; ++i) {
            int pbs = wave * 128 + i * 64;
            async_copy16(BT + (size_t)(col0 + rowS[i]) * K + k0 + gS[i] * 8,
                         &lB[buf][(size_t)pbs * 8]);
        }
    };

    const int nt = K >> 5;           // 24 (GEMM1) / 16 (GEMM2)
    stage(0, 0);
    if (nt > 2) {
        stage(32, 1);
        stage(64, 2);
        // in flight: t0(3) t1(3) t2(3); wait t0, keep t1/t2 flying
        asm volatile("s_waitcnt vmcnt(6)\n\ts_barrier" ::: "memory");
    } else if (nt > 1) {
        stage(32, 1);
        asm volatile("s_waitcnt vmcnt(3)\n\ts_barrier" ::: "memory");
    } else {
        asm volatile("s_waitcnt vmcnt(0)\n\ts_barrier" ::: "memory");
    }

    for (int t = 0; t < nt; ++t) {
        const int pb = t & 3;
        // stage writes buf (t+3)%4 == (t-1)%4: its readers (iter t-1) all
        // passed the barrier that ended iter t-1 (with lgkmcnt drained).
        if (t + 3 < nt) stage((t + 3) << 5, (t + 3) & 3);
        bf16x8 af[2], bfr[4];
#pragma unroll
        for (int tt = 0; tt < 2; ++tt) {
            int m = wm + tt * 16 + ml;
            af[tt] = *(const bf16x8*)&lA[pb][(size_t)(m * 4 + (q ^ ((m >> 1) & 3))) * 8];
        }
#pragma unroll
        for (int tt = 0; tt < 4; ++tt) {
            int n = wn + tt * 16 + ml;
            bfr[tt] = *(const bf16x8*)&lB[pb][(size_t)(n * 4 + (q ^ ((n >> 1) & 3))) * 8];
        }
#pragma unroll
        for (int tm = 0; tm < 2; ++tm)
#pragma unroll
            for (int tn = 0; tn < 4; ++tn)
                acc[tm][tn] = __builtin_amdgcn_mfma_f32_16x16x32_bf16(
                    af[tm], bfr[tn], acc[tm][tn], 0, 0, 0);
        // end-of-iter: tile t+1 landed; t+2 (and t+3 if staged) stay IN FLIGHT.
        if (t + 3 < nt)
            asm volatile("s_waitcnt vmcnt(6) lgkmcnt(0)\n\ts_barrier" ::: "memory");
        else if (t + 2 < nt)
            asm volatile("s_waitcnt vmcnt(3) lgkmcnt(0)\n\ts_barrier" ::: "memory");
        else if (t + 1 < nt)
            asm volatile("s_waitcnt vmcnt(0) lgkmcnt(0)\n\ts_barrier" ::: "memory");
        // last iteration: no barrier needed; epilogue __syncthreads covers e_lds.
    }

    float es_acc[2][4] = {};   // [tm][r]
    float ed_acc[2][4] = {};
#pragma unroll
    for (int tm = 0; tm < 2; ++tm) {
        int rbase = row0 + wm + tm * 16 + q * 4;
#pragma unroll
        for (int tn = 0; tn < 4; ++tn) {
            int col = col0 + wn + tn * 16 + ml;
            float bb = bias ? bias[col] : 0.f;
            float av = asrc[col];
            float dv = adst[col];
#pragma unroll
            for (int r = 0; r < 4; ++r) {
                int row = rbase + r;
                float val = acc[tm][tn][r] + bb;
                if (row < M)
                    Cb[(size_t)row * Nc + col] = f2bf(val);
                es_acc[tm][r] += val * av;
                ed_acc[tm][r] += val * dv;
            }
        }
    }
    // reduce over the 16-lane col groups (xor 1,2,4,8 keeps q fixed)
    const int colhalf = wave >> 1;
#pragma unroll
    for (int tm = 0; tm < 2; ++tm) {
#pragma unroll
        for (int r = 0; r < 4; ++r) {
            float es = es_acc[tm][r], ed2 = ed_acc[tm][r];
#pragma unroll
            for (int st = 1; st < 16; st <<= 1) {
                es += __shfl_xor(es, st);
                ed2 += __shfl_xor(ed2, st);
            }
            if (ml == 0) {
                int rl = wm + tm * 16 + q * 4 + r;
                e_lds[rl][colhalf][0] = es;
                e_lds[rl][colhalf][1] = ed2;
            }
        }
    }
    __syncthreads();
    if (tid < 64) {
        int row = row0 + tid;
        if (row < M) {
            float es = e_lds[tid][0][0] + e_lds[tid][1][0];
            float ed2 = e_lds[tid][0][1] + e_lds[tid][1][1];
            e_src[(size_t)row * eStride + bx] = es;
            e_dst[(size_t)row * eStride + bx] = ed2;
        }
    }
}

// ---------------------------------------------------------------- gather+softmax
// layer 1: persistent waves (R6), A/B load pipeline (R5), unnormalized softmax
// (R2), bucket-indexed (R10).
__global__ __launch_bounds__(256) void gather1_kernel(
    const ushort_t* __restrict__ h1b, const float* __restrict__ e_src,
    const float* __restrict__ e_dst, const int* __restrict__ cnt,
    const int* __restrict__ bucket, const float* __restrict__ bias,
    ushort_t* __restrict__ outb, int N)
{
    const int lane = threadIdx.x & 63;
    const int wid0 = blockIdx.x * 4 + (threadIdx.x >> 6);
    const int nw = gridDim.x * 4;

    const int h = lane >> 4;
    const bool b1 = (h & 1), b2 = (h & 2);
    const ushort_t* hp = h1b + lane * 8;
    const int c = lane * 8;
    float bias0 = bias[c],     bias1 = bias[c + 1], bias2 = bias[c + 2],
          bias3 = bias[c + 3], bias4 = bias[c + 4], bias5 = bias[c + 5],
          bias6 = bias[c + 6], bias7 = bias[c + 7];

    for (int node = __builtin_amdgcn_readfirstlane(wid0); node < N;
         node = __builtin_amdgcn_readfirstlane(node + nw)) {
        int deg = cnt[node];
        if (deg > CAP) deg = CAP;
        int beg = node * CAP, end = beg + deg;
        float4 ed = *(const float4*)&e_dst[node * 4];
        float edh = sel4(ed, b1, b2);

        f32x2 acc[4] = {};
        float s = 0.f;                   // same value in every lane of a head

        int j = beg;
        const int nb = deg >> 2;

        int4 ia, ib;
        float4 qa0, qa1, qa2, qa3, qb0, qb1, qb2, qb3;
        uint4 ua0, ua1, ua2, ua3, ub0, ub1, ub2, ub3;

        auto load4 = [&](int jj, int4& ix,
                         float4& q0, float4& q1, float4& q2, float4& q3,
                         uint4& u0, uint4& u1, uint4& u2, uint4& u3) {
            ix.x = bucket[jj];     ix.y = bucket[jj + 1];
            ix.z = bucket[jj + 2]; ix.w = bucket[jj + 3];
            q0 = *(const float4*)&e_src[ix.x * 4];
            q1 = *(const float4*)&e_src[ix.y * 4];
            q2 = *(const float4*)&e_src[ix.z * 4];
            q3 = *(const float4*)&e_src[ix.w * 4];
            u0 = *(const uint4*)&hp[(size_t)ix.x * 512];
            u1 = *(const uint4*)&hp[(size_t)ix.y * 512];
            u2 = *(const uint4*)&hp[(size_t)ix.z * 512];
            u3 = *(const uint4*)&hp[(size_t)ix.w * 512];
        };
        auto cons4 = [&](const float4& q0, const float4& q1,
                         const float4& q2, const float4& q3,
                         const uint4& u0, const uint4& u1,
                         const uint4& u2, const uint4& u3) {
            float w0 = __expf(leaky(sel4(q0, b1, b2) + edh));
            float w1 = __expf(leaky(sel4(q1, b1, b2) + edh));
            float w2 = __expf(leaky(sel4(q2, b1, b2) + edh));
            float w3 = __expf(leaky(sel4(q3, b1, b2) + edh));
            s += (w0 + w1) + (w2 + w3);
            f32x2 wv;
            wv.x = w0; wv.y = w0;
            acc[0] += unpack2(u0.x) * wv; acc[1] += unpack2(u0.y) * wv;
            acc[2] += unpack2(u0.z) * wv; acc[3] += unpack2(u0.w) * wv;
            wv.x = w1; wv.y = w1;
            acc[0] += unpack2(u1.x) * wv; acc[1] += unpack2(u1.y) * wv;
            acc[2] += unpack2(u1.z) * wv; acc[3] += unpack2(u1.w) * wv;
            wv.x = w2; wv.y = w2;
            acc[0] += unpack2(u2.x) * wv; acc[1] += unpack2(u2.y) * wv;
            acc[2] += unpack2(u2.z) * wv; acc[3] += unpack2(u2.w) * wv;
            wv.x = w3; wv.y = w3;
            acc[0] += unpack2(u3.x) * wv; acc[1] += unpack2(u3.y) * wv;
            acc[2] += unpack2(u3.z) * wv; acc[3] += unpack2(u3.w) * wv;
        };

        if (nb > 0) {
            load4(j, ia, qa0, qa1, qa2, qa3, ua0, ua1, ua2, ua3); j += 4;
            int b = 1;
            for (; b + 1 < nb; b += 2) {
                load4(j, ib, qb0, qb1, qb2, qb3, ub0, ub1, ub2, ub3); j += 4;
                cons4(qa0, qa1, qa2, qa3, ua0, ua1, ua2, ua3);
                load4(j, ia, qa0, qa1, qa2, qa3, ua0, ua1, ua2, ua3); j += 4;
                cons4(qb0, qb1, qb2, qb3, ub0, ub1, ub2, ub3);
            }
            if (b < nb) {
                load4(j, ib, qb0, qb1, qb2, qb3, ub0, ub1, ub2, ub3); j += 4;
                cons4(qa0, qa1, qa2, qa3, ua0, ua1, ua2, ua3);
                cons4(qb0, qb1, qb2, qb3, ub0, ub1, ub2, ub3);
            } else {
                cons4(qa0, qa1, qa2, qa3, ua0, ua1, ua2, ua3);
            }
        }
        for (; j < end; ++j) {
            int s0 = bucket[j];
            float4 q0 = *(const float4*)&e_src[s0 * 4];
            float w0 = __expf(leaky(sel4(q0, b1, b2) + edh));
            s += w0;
            uint4 u0 = *(const uint4*)&hp[(size_t)s0 * 512];
            f32x2 wv; wv.x = w0; wv.y = w0;
            acc[0] += unpack2(u0.x) * wv; acc[1] += unpack2(u0.y) * wv;
            acc[2] += unpack2(u0.z) * wv; acc[3] += unpack2(u0.w) * wv;
        }
        float rs = 1.f / (s + 1e-16f);
        ushort_t o[8];
        float r0, r1;
        r0 = acc[0].x * rs + bias0; r1 = acc[0].y * rs + bias1;
        r0 = (r0 > 0.f) ? r0 : (__expf(r0) - 1.f);
        r1 = (r1 > 0.f) ? r1 : (__expf(r1) - 1.f);
        o[0] = f2bf(r0); o[1] = f2bf(r1);
        r0 = acc[1].x * rs + bias2; r1 = acc[1].y * rs + bias3;
        r0 = (r0 > 0.f) ? r0 : (__expf(r0) - 1.f);
        r1 = (r1 > 0.f) ? r1 : (__expf(r1) - 1.f);
        o[2] = f2bf(r0); o[3] = f2bf(r1);
        r0 = acc[2].x * rs + bias4; r1 = acc[2].y * rs + bias5;
        r0 = (r0 > 0.f) ? r0 : (__expf(r0) - 1.f);
        r1 = (r1 > 0.f) ? r1 : (__expf(r1) - 1.f);
        o[4] = f2bf(r0); o[5] = f2bf(r1);
        r0 = acc[3].x * rs + bias6; r1 = acc[3].y * rs + bias7;
        r0 = (r0 > 0.f) ? r0 : (__expf(r0) - 1.f);
        r1 = (r1 > 0.f) ? r1 : (__expf(r1) - 1.f);
        o[6] = f2bf(r0); o[7] = f2bf(r1);
        *(uint4*)&outb[(size_t)node * 512 + c] = *(uint4*)o;
    }
}

// layer 2: persistent waves, 1 head; bucket-indexed; fp32 out.
__global__ __launch_bounds__(256) void gather2_kernel(
    const ushort_t* __restrict__ h2b, const float* __restrict__ e_src,
    const float* __restrict__ e_dst, const int* __restrict__ cnt,
    const int* __restrict__ bucket, const float* __restrict__ bias,
    float* __restrict__ out, int N)
{
    const int lane = threadIdx.x & 63;
    const int wid0 = blockIdx.x * 4 + (threadIdx.x >> 6);
    const int nw = gridDim.x * 4;

    const ushort_t* hp = h2b + lane * 2;
    float biasA = bias[lane * 2], biasB = bias[lane * 2 + 1];

    for (int node = __builtin_amdgcn_readfirstlane(wid0); node < N;
         node = __builtin_amdgcn_readfirstlane(node + nw)) {
        int deg = cnt[node];
        if (deg > CAP) deg = CAP;
        int beg = node * CAP, end = beg + deg;
        float ed = e_dst[node];

        f32x2 acc = { 0.f, 0.f };
        float s = 0.f;

        int j = beg;
        const int nb = deg >> 2;

        int4 ia, ib;
        float fa0, fa1, fa2, fa3, fb0, fb1, fb2, fb3;
        unsigned ua0, ua1, ua2, ua3, ub0, ub1, ub2, ub3;

        auto load4 = [&](int jj, int4& ix,
                         float& f0, float& f1, float& f2, float& f3,
                         unsigned& u0, unsigned& u1, unsigned& u2, unsigned& u3) {
            ix.x = bucket[jj];     ix.y = bucket[jj + 1];
            ix.z = bucket[jj + 2]; ix.w = bucket[jj + 3];
            f0 = e_src[ix.x]; f1 = e_src[ix.y];
            f2 = e_src[ix.z]; f3 = e_src[ix.w];
            u0 = *(const unsigned*)&hp[(size_t)ix.x * 128];
            u1 = *(const unsigned*)&hp[(size_t)ix.y * 128];
            u2 = *(const unsigned*)&hp[(size_t)ix.z * 128];
            u3 = *(const unsigned*)&hp[(size_t)ix.w * 128];
        };
        auto cons4 = [&](float f0, float f1, float f2, float f3,
                         unsigned u0, unsigned u1, unsigned u2, unsigned u3) {
            float w0 = __expf(leaky(f0 + ed));
            float w1 = __expf(leaky(f1 + ed));
            float w2 = __expf(leaky(f2 + ed));
            float w3 = __expf(leaky(f3 + ed));
            s += (w0 + w1) + (w2 + w3);
            f32x2 w0v = { w0, w0 }, w1v = { w1, w1 }, w2v = { w2, w2 }, w3v = { w3, w3 };
            acc += unpack2(u0) * w0v;
            acc += unpack2(u1) * w1v;
            acc += unpack2(u2) * w2v;
            acc += unpack2(u3) * w3v;
        };

        if (nb > 0) {
            load4(j, ia, fa0, fa1, fa2, fa3, ua0, ua1, ua2, ua3); j += 4;
            int b = 1;
            for (; b + 1 < nb; b += 2) {
                load4(j, ib, fb0, fb1, fb2, fb3, ub0, ub1, ub2, ub3); j += 4;
                cons4(fa0, fa1, fa2, fa3, ua0, ua1, ua2, ua3);
                load4(j, ia, fa0, fa1, fa2, fa3, ua0, ua1, ua2, ua3); j += 4;
                cons4(fb0, fb1, fb2, fb3, ub0, ub1, ub2, ub3);
            }
            if (b < nb) {
                load4(j, ib, fb0, fb1, fb2, fb3, ub0, ub1, ub2, ub3); j += 4;
                cons4(fa0, fa1, fa2, fa3, ua0, ua1, ua2, ua3);
                cons4(fb0, fb1, fb2, fb3, ub0, ub1, ub2, ub3);
            } else {
                cons4(fa0, fa1, fa2, fa3, ua0, ua1, ua2, ua3);
            }
        }
        for (; j < end; ++j) {
            int s0 = bucket[j];
            float w0 = __expf(leaky(e_src[s0] + ed));
            s += w0;
            unsigned u0 = *(const unsigned*)&hp[(size_t)s0 * 128];
            f32x2 w0v = { w0, w0 };
            acc += unpack2(u0) * w0v;
        }
        float rs = 1.f / (s + 1e-16f);
        float2 o = make_float2(acc.x * rs + biasA, acc.y * rs + biasB);
        *(float2*)&out[(size_t)node * 128 + lane * 2] = o;
    }
}

// ---------------------------------------------------------------- launch
extern "C" void kernel_launch(void* const* d_in, const int* in_sizes, int n_in,
                              void* d_out, int out_size, void* d_ws, size_t ws_size,
                              hipStream_t stream) {
    const float* x      = (const float*)d_in[0];
    const int*   ei     = (const int*)  d_in[1];
    const float* sent   = (const float*)d_in[2];
    const float* W1     = (const float*)d_in[3];
    const float* a1_src = (const float*)d_in[4];
    const float* a1_dst = (const float*)d_in[5];
    const float* b1     = (const float*)d_in[6];
    const float* W2     = (const float*)d_in[7];
    const float* a2_src = (const float*)d_in[8];
    const float* a2_dst = (const float*)d_in[9];
    const float* b2     = (const float*)d_in[10];
    float* out = (float*)d_out;

    const int N = in_sizes[0] / 768;   // 20000
    const int E = in_sizes[1] / 2;     // 320000

    char* p = (char*)d_ws;
    auto carve = [&](size_t bytes) {
        char* q = p;
        p += (bytes + 255) & ~(size_t)255;
        return q;
    };
    ushort_t* h1b = (ushort_t*)carve((size_t)N * 512 * 2);
    char* shared_region = carve((size_t)N * 768 * 2);   // x_bf16 dead after GEMM1
    ushort_t* x_bf16 = (ushort_t*)shared_region;
    ushort_t* h_elu_b = (ushort_t*)shared_region;
    ushort_t* h2b = (ushort_t*)carve((size_t)N * 128 * 2);
    ushort_t* W1T = (ushort_t*)carve((size_t)512 * 768 * 2);
    ushort_t* W2T = (ushort_t*)carve((size_t)128 * 512 * 2);
    float* e_src1 = (float*)carve((size_t)N * 4 * 4);
    float* e_dst1 = (float*)carve((size_t)N * 4 * 4);
    float* e_src2 = (float*)carve((size_t)N * 4);
    float* e_dst2 = (float*)carve((size_t)N * 4);
    // cnt and svec carved ADJACENTLY so one memset zeroes both
    int*   cnt    = (int*)carve((size_t)N * 4);
    float* svec   = (float*)carve(512 * 4);
    int*   bucket = (int*)carve((size_t)N * CAP * 4);

    size_t nx = (size_t)N * 768;
    int nbCast = (int)((nx / 8 + 255) / 256);       // 7500
    int nbScat = (E + 255) / 256;                   // 1250
    int nbPrep = 384 + 64 + 32 + nbCast + nbScat;   // 9230

    // zero bucket counters + svec accumulators in one memset
    size_t zero_span = (size_t)((char*)(svec + 512) - (char*)cnt);
    hipMemsetAsync(cnt, 0, zero_span, stream);

    // fused prep + bucket-scatter (count/scan/scatter dispatches eliminated)
    prep_scatter_kernel<<<nbPrep, 256, 0, stream>>>(
        x, x_bf16, nx, W1, W1T, W2, W2T, sent, svec, ei, E, cnt, bucket, nbCast);

    // pad row-block count (64-row tiles) to a multiple of 8 for the XCD
    // swizzle; padded blocks clamp their A rows and skip all guarded writes.
    int nyPad = (((N + 63) / 64) + 7) & ~7;   // 320 for N=20000

    // GEMM1: h1b = bf16(x @ W1[:768] + svec), fused e1  [N,512]
    mfma_gemm_kernel<<<dim3(4, nyPad), 256, 0, stream>>>(
        x_bf16, W1T, svec, h1b, a1_src, a1_dst, e_src1, e_dst1, 4, N, 768, 512);

    // layer-1 attention: persistent waves, 2048 blocks = 8/CU
    gather1_kernel<<<2048, 256, 0, stream>>>(
        h1b, e_src1, e_dst1, cnt, bucket, b1, h_elu_b, N);

    // GEMM2: h2b = bf16(h_elu @ W2), fused e2  [N,128]
    mfma_gemm_kernel<<<dim3(1, nyPad), 256, 0, stream>>>(
        h_elu_b, W2T, nullptr, h2b, a2_src, a2_dst, e_src2, e_dst2, 1, N, 512, 128);

    // layer-2 attention: persistent waves
    gather2_kernel<<<2048, 256, 0, stream>>>(
        h2b, e_src2, e_dst2, cnt, bucket, b2, out, N);
}